// Round 1
// 620.123 us; speedup vs baseline: 1.0651x; 1.0651x over previous
//
#include <hip/hip_runtime.h>
#include <math.h>

#define B_    32
#define HH    56
#define WW_   56
#define C_    192
#define WS_   7
#define SHIFT_ 3
#define HEADS_ 6
#define DH    32
#define N_    49
#define NWIN  2048
#define ROWS  100352
#define HID_  768
#define QKVN  576

typedef __bf16 bfr;
typedef __bf16 bf8 __attribute__((ext_vector_type(8)));
typedef float  f32x4 __attribute__((ext_vector_type(4)));

#define MFMA16(a,b,c) __builtin_amdgcn_mfma_f32_16x16x32_bf16(a,b,c,0,0,0)

// ---- ws layout (bf16 elements) ----
#define OQW   0         // qkvwT [576][192]
#define OPW   110592    // projwT[192][192]
#define OW1   147456    // w1T   [768][192]
#define OW2   294912    // w2T   [192][768]
#define OBM   442368    // bmask [6][64][64][64]  (bias+mask, pads = -1e30)
#define WTOT  442368
#define BMTOT 1572864   // 6*64*64*64

// ================= k_prep: transpose + fp32->bf16 all weights =================
__global__ __launch_bounds__(256) void k_prep(
    const float* __restrict__ qkvw, const float* __restrict__ projw,
    const float* __restrict__ w1,   const float* __restrict__ w2,
    bfr* __restrict__ wsp)
{
  int idx = blockIdx.x*256 + threadIdx.x;
  if (idx >= WTOT) return;
  if (idx < OPW)      { int i=idx;      int n=i/192, k=i%192; wsp[idx] = (bfr)qkvw[k*QKVN + n]; }
  else if (idx < OW1) { int i=idx-OPW;  int n=i/192, k=i%192; wsp[idx] = (bfr)projw[k*C_ + n]; }
  else if (idx < OW2) { int i=idx-OW1;  int n=i/192, k=i%192; wsp[idx] = (bfr)w1[k*HID_ + n]; }
  else                { int i=idx-OW2;  int n=i/768, k=i%768; wsp[idx] = (bfr)w2[k*C_ + n]; }
}

// ================= k_prep2: bmask[head][wi][row64][col64] = bias + mask (pads -1e30) =========
__global__ __launch_bounds__(256) void k_prep2(
    const float* __restrict__ btab, const int* __restrict__ rel,
    const float* __restrict__ mask, bfr* __restrict__ bm)
{
  int idx = blockIdx.x*256 + threadIdx.x;   // [head][wi][row][col]
  if (idx >= BMTOT) return;
  int col = idx & 63, row = (idx>>6) & 63, wi = (idx>>12) & 63, head = idx>>18;
  float v = -1e30f;
  if (row < N_ && col < N_) {
    int e = row*N_ + col;
    v = btab[rel[e]*HEADS_ + head] + mask[(size_t)wi*N_*N_ + e];
  }
  bm[idx] = (bfr)v;
}

// ================= Kernel 1: LN1+shift+QKV+attn+proj+residual, head-pair streamed ============
// LDS (bytes):
#define SM_HS 0        // bfr hs[64][200]          25600  (LN'd input, persists)
#define SM_QS 25600    // bfr qs[2][64][36]         9216
#define SM_KS 34816    // bfr ks[2][64][36]         9216
#define SM_VT 44032    // bfr vT[2][32][72]         9216
#define SM_P  53248    // bfr P[64][72]             9216
#define SM_OV 62464    // bfr ov[64][36]            4608
#define SM_SR 67072    // int srows[64]              256
#define SM1_TOT 67328
#define HSP 200

__global__ __launch_bounds__(256) void k_attn(
    const float* __restrict__ x,
    const float* __restrict__ n1w, const float* __restrict__ n1b,
    const bfr*   __restrict__ wsp,
    const float* __restrict__ qkvb,
    const float* __restrict__ projb,
    float* __restrict__ out)
{
  __shared__ char smem[SM1_TOT];
  bfr*   hs    = (bfr*)(smem + SM_HS);
  bfr*   qs    = (bfr*)(smem + SM_QS);
  bfr*   ks    = (bfr*)(smem + SM_KS);
  bfr*   vT    = (bfr*)(smem + SM_VT);
  bfr*   P     = (bfr*)(smem + SM_P);
  bfr*   ov    = (bfr*)(smem + SM_OV);
  int*   srows = (int*)(smem + SM_SR);
  float* pj    = (float*)smem;   // overlay [64][196] fp32 = 50176 B over hs/qs/ks/vT

  const f32x4 ZERO4 = {0.f, 0.f, 0.f, 0.f};

  int win  = blockIdx.x;
  int tid  = threadIdx.x;
  int lane = tid & 63, wave = tid >> 6;
  int ln15 = lane & 15, quad = lane >> 4;
  int wi   = win & 63;

  // ---- srows + zero hs ----
  if (tid < N_) {
    int bb = win >> 6;
    int wh = wi >> 3, ww = wi & 7;
    int th = tid / WS_, tw = tid % WS_;
    int sh = wh*WS_ + th + SHIFT_; if (sh >= HH) sh -= HH;
    int sw = ww*WS_ + tw + SHIFT_; if (sw >= WW_) sw -= WW_;
    srows[tid] = bb*HH*WW_ + sh*WW_ + sw;
  }
  {
    int* hz = (int*)hs;
    for (int i = tid; i < 64*HSP/2; i += 256) hz[i] = 0;
  }
  __syncthreads();
  // ---- LN1 -> hs ----
  for (int r = wave; r < N_; r += 4) {
    const float* xr = x + (size_t)srows[r]*C_;
    float v0 = xr[lane], v1 = xr[lane+64], v2 = xr[lane+128];
    float s = v0+v1+v2, q = v0*v0+v1*v1+v2*v2;
    #pragma unroll
    for (int m = 32; m; m >>= 1) { s += __shfl_xor(s, m); q += __shfl_xor(q, m); }
    float mu = s*(1.f/C_), var = q*(1.f/C_) - mu*mu;
    float rs = rsqrtf(var + 1e-5f);
    hs[r*HSP + lane]     = (bfr)((v0-mu)*rs*n1w[lane]     + n1b[lane]);
    hs[r*HSP + lane+64]  = (bfr)((v1-mu)*rs*n1w[lane+64]  + n1b[lane+64]);
    hs[r*HSP + lane+128] = (bfr)((v2-mu)*rs*n1w[lane+128] + n1b[lane+128]);
  }
  __syncthreads();

  const bfr* qkvwT  = wsp + OQW;
  const bfr* projwT = wsp + OPW;
  const bfr* bmask  = wsp + OBM;

  f32x4 accp[3][4];   // proj accumulators, persist across heads
  #pragma unroll
  for (int j=0;j<3;j++)
    #pragma unroll
    for (int mt=0;mt<4;mt++) accp[j][mt] = ZERO4;

  for (int pair = 0; pair < 3; pair++) {
    // ---- QKV for this pair: wave handles col-tile (wave) of q(j=0),k(j=1),v(j=2) ----
    {
      f32x4 acc[3][4];
      #pragma unroll
      for (int j=0;j<3;j++)
        #pragma unroll
        for (int mt=0;mt<4;mt++) acc[j][mt] = ZERO4;
      for (int k0 = 0; k0 < C_; k0 += 32) {
        bf8 afr[4];
        #pragma unroll
        for (int mt=0;mt<4;mt++)
          afr[mt] = *(const bf8*)&hs[(mt*16+ln15)*HSP + k0 + quad*8];
        #pragma unroll
        for (int j=0;j<3;j++) {
          int colg = j*192 + pair*64 + wave*16 + ln15;
          bf8 bw = *(const bf8*)&qkvwT[(size_t)colg*192 + k0 + quad*8];
          #pragma unroll
          for (int mt=0;mt<4;mt++) acc[j][mt] = MFMA16(afr[mt], bw, acc[j][mt]);
        }
      }
      int colp = wave*16 + ln15;         // within-pair col 0..63
      int hl = colp >> 5, d = colp & 31;
      #pragma unroll
      for (int j=0;j<3;j++) {
        float bias = qkvb[j*192 + pair*64 + colp];
        #pragma unroll
        for (int mt=0;mt<4;mt++)
          #pragma unroll
          for (int r=0;r<4;r++) {
            int row = mt*16 + quad*4 + r;
            float vv = acc[j][mt][r] + bias;
            if (j == 0)      qs[(hl*64+row)*36 + d] = (bfr)(vv*0.17677669529663689f);
            else if (j == 1) ks[(hl*64+row)*36 + d] = (bfr)vv;
            else             vT[(hl*32+d)*72 + row] = (bfr)vv;
          }
      }
    }
    __syncthreads();

    for (int hl = 0; hl < 2; hl++) {
      int head = pair*2 + hl;
      // ---- QK^T: wave owns rows wave*16..+15, all 64 cols ----
      float val[4][4];   // [nt][r]
      {
        bf8 aq = *(const bf8*)&qs[(hl*64 + wave*16 + ln15)*36 + quad*8];
        #pragma unroll
        for (int nt = 0; nt < 4; nt++) {
          bf8 bk = *(const bf8*)&ks[(hl*64 + nt*16 + ln15)*36 + quad*8];
          f32x4 c = MFMA16(aq, bk, ZERO4);
          #pragma unroll
          for (int r=0;r<4;r++) val[nt][r] = c[r];
        }
      }
      // bias+mask (pads already -1e30 in table)
      {
        const bfr* bmh = bmask + (((size_t)head*64 + wi) << 12);
        #pragma unroll
        for (int nt=0;nt<4;nt++)
          #pragma unroll
          for (int r=0;r<4;r++)
            val[nt][r] += (float)bmh[(wave*16 + quad*4 + r)*64 + nt*16 + ln15];
      }
      // ---- register softmax over 64 cols (4 regs x 16 lanes) ----
      {
        float mx[4], sum[4];
        #pragma unroll
        for (int r=0;r<4;r++) {
          mx[r] = fmaxf(fmaxf(val[0][r], val[1][r]), fmaxf(val[2][r], val[3][r]));
          #pragma unroll
          for (int m = 1; m < 16; m <<= 1) mx[r] = fmaxf(mx[r], __shfl_xor(mx[r], m));
        }
        #pragma unroll
        for (int nt=0;nt<4;nt++)
          #pragma unroll
          for (int r=0;r<4;r++) val[nt][r] = __expf(val[nt][r] - mx[r]);
        #pragma unroll
        for (int r=0;r<4;r++) {
          sum[r] = val[0][r] + val[1][r] + val[2][r] + val[3][r];
          #pragma unroll
          for (int m = 1; m < 16; m <<= 1) sum[r] += __shfl_xor(sum[r], m);
          sum[r] = 1.f / sum[r];
        }
        #pragma unroll
        for (int nt=0;nt<4;nt++)
          #pragma unroll
          for (int r=0;r<4;r++)
            P[(wave*16 + quad*4 + r)*72 + nt*16 + ln15] = (bfr)(val[nt][r]*sum[r]);
      }
      __syncthreads();
      // ---- PV: wave owns rows wave*16..+15, d-tiles nt=0..1 ----
      #pragma unroll
      for (int nt = 0; nt < 2; nt++) {
        f32x4 c = ZERO4;
        #pragma unroll
        for (int k0 = 0; k0 < 64; k0 += 32) {
          bf8 ap = *(const bf8*)&P[(wave*16 + ln15)*72 + k0 + quad*8];
          bf8 bv = *(const bf8*)&vT[(hl*32 + nt*16 + ln15)*72 + k0 + quad*8];
          c = MFMA16(ap, bv, c);
        }
        #pragma unroll
        for (int r=0;r<4;r++)
          ov[(wave*16 + quad*4 + r)*36 + nt*16 + ln15] = (bfr)c[r];
      }
      __syncthreads();
      // ---- proj K-step for this head (K=32 chunk at head*32) ----
      {
        bf8 afr[4];
        #pragma unroll
        for (int mt=0;mt<4;mt++)
          afr[mt] = *(const bf8*)&ov[(mt*16+ln15)*36 + quad*8];
        #pragma unroll
        for (int j=0;j<3;j++) {
          int col = (wave*3+j)*16 + ln15;
          bf8 bw = *(const bf8*)&projwT[(size_t)col*192 + head*32 + quad*8];
          #pragma unroll
          for (int mt=0;mt<4;mt++) accp[j][mt] = MFMA16(afr[mt], bw, accp[j][mt]);
        }
      }
    }
  }

  // ---- epilogue: bias -> pj overlay -> coalesced residual+scatter ----
  #pragma unroll
  for (int j=0;j<3;j++) {
    int col = (wave*3+j)*16 + ln15;
    float pb = projb[col];
    #pragma unroll
    for (int mt=0;mt<4;mt++)
      #pragma unroll
      for (int r=0;r<4;r++)
        pj[(mt*16 + quad*4 + r)*196 + col] = accp[j][mt][r] + pb;
  }
  __syncthreads();
  for (int idx = tid; idx < N_*C_; idx += 256) {
    int n = idx / C_, c = idx % C_;
    size_t gr = (size_t)srows[n]*C_ + c;
    out[gr] = x[gr] + pj[n*196 + c];
  }
}

// ================= Kernel 2: LN2 + fc1 + GELU + fc2 + residual, 32 rows/block ================
// Chunked hidden: 4 chunks of 192 cols, fc2 accumulated across chunks.
// LDS: ts[32][200] bf16 (12800) + hidc[32][200] bf16 (12800) = 25600 B -> 6 blocks/CU.
// st f32[32][196] (25088) overlays ts+hidc after last use.
#define SM2_TS  0
#define SM2_HID 12800
#define SM2_TOT 25600

__global__ __launch_bounds__(256) void k_mlp(
    float* __restrict__ y,
    const float* __restrict__ n2w, const float* __restrict__ n2b,
    const bfr* __restrict__ wsp,
    const float* __restrict__ b1, const float* __restrict__ b2)
{
  __shared__ char smem[SM2_TOT];
  bfr*   ts   = (bfr*)(smem + SM2_TS);
  bfr*   hidc = (bfr*)(smem + SM2_HID);
  float* st   = (float*)smem;       // overlay after ts/hidc dead

  const f32x4 ZERO4 = {0.f, 0.f, 0.f, 0.f};

  int r0 = blockIdx.x * 32;
  int tid = threadIdx.x;
  int lane = tid & 63, wave = tid >> 6;
  int ln15 = lane & 15, quad = lane >> 4;

  // ---- LN2 (keep x rows in registers for the residual epilogue) ----
  float xv[8][3];
  #pragma unroll
  for (int i = 0; i < 8; i++) {
    int r = wave + i*4;
    const float* yr = y + (size_t)(r0 + r)*C_;
    float v0 = yr[lane], v1 = yr[lane+64], v2 = yr[lane+128];
    xv[i][0] = v0; xv[i][1] = v1; xv[i][2] = v2;
    float s = v0+v1+v2, q = v0*v0+v1*v1+v2*v2;
    #pragma unroll
    for (int m = 32; m; m >>= 1) { s += __shfl_xor(s, m); q += __shfl_xor(q, m); }
    float mu = s*(1.f/C_), var = q*(1.f/C_) - mu*mu;
    float rs = rsqrtf(var + 1e-5f);
    ts[r*HSP + lane]     = (bfr)((v0-mu)*rs*n2w[lane]     + n2b[lane]);
    ts[r*HSP + lane+64]  = (bfr)((v1-mu)*rs*n2w[lane+64]  + n2b[lane+64]);
    ts[r*HSP + lane+128] = (bfr)((v2-mu)*rs*n2w[lane+128] + n2b[lane+128]);
  }
  __syncthreads();

  const bfr* w1T = wsp + OW1;
  const bfr* w2T = wsp + OW2;

  f32x4 accp[3][2];   // fc2 accumulators, persist across chunks
  #pragma unroll
  for (int j=0;j<3;j++)
    #pragma unroll
    for (int mt=0;mt<2;mt++) accp[j][mt] = ZERO4;

  for (int c = 0; c < 4; c++) {
    // ---- fc1 chunk: M=32, N=192 (cols c*192..+191), K=192 ----
    {
      f32x4 acc[3][2];
      #pragma unroll
      for (int j=0;j<3;j++)
        #pragma unroll
        for (int mt=0;mt<2;mt++) acc[j][mt] = ZERO4;
      for (int k0 = 0; k0 < C_; k0 += 32) {
        bf8 afr[2];
        #pragma unroll
        for (int mt=0;mt<2;mt++)
          afr[mt] = *(const bf8*)&ts[(mt*16+ln15)*HSP + k0 + quad*8];
        #pragma unroll
        for (int j=0;j<3;j++) {
          int gcol = (c*12 + wave*3 + j)*16 + ln15;
          bf8 bw = *(const bf8*)&w1T[(size_t)gcol*192 + k0 + quad*8];
          #pragma unroll
          for (int mt=0;mt<2;mt++) acc[j][mt] = MFMA16(afr[mt], bw, acc[j][mt]);
        }
      }
      // GELU (tanh-form: g*sigmoid(1.59576912*g + 0.07135482*g^3), |err|<3e-4 << bf16 lsb)
      #pragma unroll
      for (int j=0;j<3;j++) {
        int colc = (wave*3 + j)*16 + ln15;
        float bb = b1[c*192 + colc];
        #pragma unroll
        for (int mt=0;mt<2;mt++)
          #pragma unroll
          for (int r=0;r<4;r++) {
            int row = mt*16 + quad*4 + r;
            float g = acc[j][mt][r] + bb;
            float u = g*(1.5957691216f + 0.0713548170f*g*g);
            hidc[row*HSP + colc] = (bfr)(g / (1.f + __expf(-u)));
          }
      }
    }
    __syncthreads();
    // ---- fc2 partial: M=32, N=192, K=192 (k-range c*192..+191) ----
    for (int k0 = 0; k0 < 192; k0 += 32) {
      bf8 afr[2];
      #pragma unroll
      for (int mt=0;mt<2;mt++)
        afr[mt] = *(const bf8*)&hidc[(mt*16+ln15)*HSP + k0 + quad*8];
      #pragma unroll
      for (int j=0;j<3;j++) {
        int col = (wave*3+j)*16 + ln15;
        bf8 bw = *(const bf8*)&w2T[(size_t)col*768 + c*192 + k0 + quad*8];
        #pragma unroll
        for (int mt=0;mt<2;mt++) accp[j][mt] = MFMA16(afr[mt], bw, accp[j][mt]);
      }
    }
    __syncthreads();   // hidc reads done before next chunk's writes (or st overlay)
  }

  // ---- epilogue: bias -> st overlay (over ts/hidc, both dead) ----
  #pragma unroll
  for (int j=0;j<3;j++) {
    int col = (wave*3+j)*16 + ln15;
    float bb = b2[col];
    #pragma unroll
    for (int mt=0;mt<2;mt++)
      #pragma unroll
      for (int r=0;r<4;r++) {
        int row = mt*16 + quad*4 + r;
        st[row*196 + col] = accp[j][mt][r] + bb;
      }
  }
  __syncthreads();
  // residual from registers, coalesced in-place write (no y re-read)
  #pragma unroll
  for (int i = 0; i < 8; i++) {
    int r = wave + i*4;
    float* yr = y + (size_t)(r0 + r)*C_;
    yr[lane]      = xv[i][0] + st[r*196 + lane];
    yr[lane+64]   = xv[i][1] + st[r*196 + lane+64];
    yr[lane+128]  = xv[i][2] + st[r*196 + lane+128];
  }
}

extern "C" void kernel_launch(void* const* d_in, const int* in_sizes, int n_in,
                              void* d_out, int out_size, void* d_ws, size_t ws_size,
                              hipStream_t stream) {
  const float* x     = (const float*)d_in[0];
  const float* n1w   = (const float*)d_in[1];
  const float* n1b   = (const float*)d_in[2];
  const float* qkvw  = (const float*)d_in[3];
  const float* qkvb  = (const float*)d_in[4];
  const float* btab  = (const float*)d_in[5];
  const float* projw = (const float*)d_in[6];
  const float* projb = (const float*)d_in[7];
  const float* n2w   = (const float*)d_in[8];
  const float* n2b   = (const float*)d_in[9];
  const float* w1    = (const float*)d_in[10];
  const float* b1    = (const float*)d_in[11];
  const float* w2    = (const float*)d_in[12];
  const float* b2    = (const float*)d_in[13];
  const float* mask  = (const float*)d_in[14];
  const int*   rel   = (const int*)d_in[15];
  float* out = (float*)d_out;
  bfr*   wsp = (bfr*)d_ws;   // (442368 + 1572864) * 2 B ~= 4.03 MB

  k_prep<<<(WTOT+255)/256, 256, 0, stream>>>(qkvw, projw, w1, w2, wsp);
  k_prep2<<<(BMTOT+255)/256, 256, 0, stream>>>(btab, rel, mask, wsp + OBM);
  k_attn<<<NWIN, 256, 0, stream>>>(x, n1w, n1b, wsp, qkvb, projb, out);
  k_mlp<<<ROWS/32, 256, 0, stream>>>(out, n2w, n2b, wsp, b1, b2);
}

// Round 2
// 571.976 us; speedup vs baseline: 1.1548x; 1.0842x over previous
//
#include <hip/hip_runtime.h>
#include <math.h>

#define B_    32
#define HH    56
#define WW_   56
#define C_    192
#define WS_   7
#define SHIFT_ 3
#define HEADS_ 6
#define DH    32
#define N_    49
#define NWIN  2048
#define ROWS  100352
#define HID_  768
#define QKVN  576

typedef __bf16 bfr;
typedef __bf16 bf8 __attribute__((ext_vector_type(8)));
typedef float  f32x4 __attribute__((ext_vector_type(4)));

#define MFMA16(a,b,c) __builtin_amdgcn_mfma_f32_16x16x32_bf16(a,b,c,0,0,0)

// ---- ws layout (bf16 elements) ----
#define OQW   0         // qkvwT [576][192]
#define OPW   110592    // projwT[192][192]
#define OW1   147456    // w1T   [768][192]
#define OW2   294912    // w2T   [192][768]
#define OBM   442368    // bmask [6][64][64][64]  (bias+mask, pads = -1e30)
#define WTOT  442368
#define BMTOT 1572864   // 6*64*64*64

// ================= k_prep: transpose + fp32->bf16 all weights =================
__global__ __launch_bounds__(256) void k_prep(
    const float* __restrict__ qkvw, const float* __restrict__ projw,
    const float* __restrict__ w1,   const float* __restrict__ w2,
    bfr* __restrict__ wsp)
{
  int idx = blockIdx.x*256 + threadIdx.x;
  if (idx >= WTOT) return;
  if (idx < OPW)      { int i=idx;      int n=i/192, k=i%192; wsp[idx] = (bfr)qkvw[k*QKVN + n]; }
  else if (idx < OW1) { int i=idx-OPW;  int n=i/192, k=i%192; wsp[idx] = (bfr)projw[k*C_ + n]; }
  else if (idx < OW2) { int i=idx-OW1;  int n=i/192, k=i%192; wsp[idx] = (bfr)w1[k*HID_ + n]; }
  else                { int i=idx-OW2;  int n=i/768, k=i%768; wsp[idx] = (bfr)w2[k*C_ + n]; }
}

// ================= k_prep2: bmask[head][wi][row64][col64] = bias + mask (pads -1e30) =========
__global__ __launch_bounds__(256) void k_prep2(
    const float* __restrict__ btab, const int* __restrict__ rel,
    const float* __restrict__ mask, bfr* __restrict__ bm)
{
  int idx = blockIdx.x*256 + threadIdx.x;   // [head][wi][row][col]
  if (idx >= BMTOT) return;
  int col = idx & 63, row = (idx>>6) & 63, wi = (idx>>12) & 63, head = idx>>18;
  float v = -1e30f;
  if (row < N_ && col < N_) {
    int e = row*N_ + col;
    v = btab[rel[e]*HEADS_ + head] + mask[(size_t)wi*N_*N_ + e];
  }
  bm[idx] = (bfr)v;
}

// ================= Kernel 1: LN1+shift+QKV+attn+proj+residual, head-pair streamed ============
// LDS (bytes):
#define SM_HS 0        // bfr hs[64][200]          25600  (LN'd input, persists)
#define SM_QS 25600    // bfr qs[2][64][36]         9216
#define SM_KS 34816    // bfr ks[2][64][36]         9216
#define SM_VT 44032    // bfr vT[2][32][72]         9216
#define SM_P  53248    // bfr P[64][72]             9216
#define SM_OV 62464    // bfr ov[64][36]            4608
#define SM_SR 67072    // int srows[64]              256
#define SM1_TOT 67328
#define HSP 200

__global__ __launch_bounds__(256) void k_attn(
    const float* __restrict__ x,
    const float* __restrict__ n1w, const float* __restrict__ n1b,
    const bfr*   __restrict__ wsp,
    const float* __restrict__ qkvb,
    const float* __restrict__ projb,
    float* __restrict__ out)
{
  __shared__ char smem[SM1_TOT];
  bfr*   hs    = (bfr*)(smem + SM_HS);
  bfr*   qs    = (bfr*)(smem + SM_QS);
  bfr*   ks    = (bfr*)(smem + SM_KS);
  bfr*   vT    = (bfr*)(smem + SM_VT);
  bfr*   P     = (bfr*)(smem + SM_P);
  bfr*   ov    = (bfr*)(smem + SM_OV);
  int*   srows = (int*)(smem + SM_SR);
  float* pj    = (float*)smem;   // overlay [64][196] fp32 = 50176 B over hs/qs/ks/vT

  const f32x4 ZERO4 = {0.f, 0.f, 0.f, 0.f};

  int win  = blockIdx.x;
  int tid  = threadIdx.x;
  int lane = tid & 63, wave = tid >> 6;
  int ln15 = lane & 15, quad = lane >> 4;
  int wi   = win & 63;

  // ---- srows + zero hs ----
  if (tid < N_) {
    int bb = win >> 6;
    int wh = wi >> 3, ww = wi & 7;
    int th = tid / WS_, tw = tid % WS_;
    int sh = wh*WS_ + th + SHIFT_; if (sh >= HH) sh -= HH;
    int sw = ww*WS_ + tw + SHIFT_; if (sw >= WW_) sw -= WW_;
    srows[tid] = bb*HH*WW_ + sh*WW_ + sw;
  }
  {
    int* hz = (int*)hs;
    for (int i = tid; i < 64*HSP/2; i += 256) hz[i] = 0;
  }
  __syncthreads();
  // ---- LN1 -> hs ----
  for (int r = wave; r < N_; r += 4) {
    const float* xr = x + (size_t)srows[r]*C_;
    float v0 = xr[lane], v1 = xr[lane+64], v2 = xr[lane+128];
    float s = v0+v1+v2, q = v0*v0+v1*v1+v2*v2;
    #pragma unroll
    for (int m = 32; m; m >>= 1) { s += __shfl_xor(s, m); q += __shfl_xor(q, m); }
    float mu = s*(1.f/C_), var = q*(1.f/C_) - mu*mu;
    float rs = rsqrtf(var + 1e-5f);
    hs[r*HSP + lane]     = (bfr)((v0-mu)*rs*n1w[lane]     + n1b[lane]);
    hs[r*HSP + lane+64]  = (bfr)((v1-mu)*rs*n1w[lane+64]  + n1b[lane+64]);
    hs[r*HSP + lane+128] = (bfr)((v2-mu)*rs*n1w[lane+128] + n1b[lane+128]);
  }
  __syncthreads();

  const bfr* qkvwT  = wsp + OQW;
  const bfr* projwT = wsp + OPW;
  const bfr* bmask  = wsp + OBM;

  f32x4 accp[3][4];   // proj accumulators, persist across heads
  #pragma unroll
  for (int j=0;j<3;j++)
    #pragma unroll
    for (int mt=0;mt<4;mt++) accp[j][mt] = ZERO4;

  for (int pair = 0; pair < 3; pair++) {
    // ---- QKV for this pair: wave handles col-tile (wave) of q(j=0),k(j=1),v(j=2) ----
    {
      f32x4 acc[3][4];
      #pragma unroll
      for (int j=0;j<3;j++)
        #pragma unroll
        for (int mt=0;mt<4;mt++) acc[j][mt] = ZERO4;
      for (int k0 = 0; k0 < C_; k0 += 32) {
        bf8 afr[4];
        #pragma unroll
        for (int mt=0;mt<4;mt++)
          afr[mt] = *(const bf8*)&hs[(mt*16+ln15)*HSP + k0 + quad*8];
        #pragma unroll
        for (int j=0;j<3;j++) {
          int colg = j*192 + pair*64 + wave*16 + ln15;
          bf8 bw = *(const bf8*)&qkvwT[(size_t)colg*192 + k0 + quad*8];
          #pragma unroll
          for (int mt=0;mt<4;mt++) acc[j][mt] = MFMA16(afr[mt], bw, acc[j][mt]);
        }
      }
      int colp = wave*16 + ln15;         // within-pair col 0..63
      int hl = colp >> 5, d = colp & 31;
      #pragma unroll
      for (int j=0;j<3;j++) {
        float bias = qkvb[j*192 + pair*64 + colp];
        #pragma unroll
        for (int mt=0;mt<4;mt++)
          #pragma unroll
          for (int r=0;r<4;r++) {
            int row = mt*16 + quad*4 + r;
            float vv = acc[j][mt][r] + bias;
            if (j == 0)      qs[(hl*64+row)*36 + d] = (bfr)(vv*0.17677669529663689f);
            else if (j == 1) ks[(hl*64+row)*36 + d] = (bfr)vv;
            else             vT[(hl*32+d)*72 + row] = (bfr)vv;
          }
      }
    }
    __syncthreads();

    for (int hl = 0; hl < 2; hl++) {
      int head = pair*2 + hl;
      // ---- QK^T: wave owns rows wave*16..+15, all 64 cols ----
      float val[4][4];   // [nt][r]
      {
        bf8 aq = *(const bf8*)&qs[(hl*64 + wave*16 + ln15)*36 + quad*8];
        #pragma unroll
        for (int nt = 0; nt < 4; nt++) {
          bf8 bk = *(const bf8*)&ks[(hl*64 + nt*16 + ln15)*36 + quad*8];
          f32x4 c = MFMA16(aq, bk, ZERO4);
          #pragma unroll
          for (int r=0;r<4;r++) val[nt][r] = c[r];
        }
      }
      // bias+mask (pads already -1e30 in table)
      {
        const bfr* bmh = bmask + (((size_t)head*64 + wi) << 12);
        #pragma unroll
        for (int nt=0;nt<4;nt++)
          #pragma unroll
          for (int r=0;r<4;r++)
            val[nt][r] += (float)bmh[(wave*16 + quad*4 + r)*64 + nt*16 + ln15];
      }
      // ---- register softmax over 64 cols (4 regs x 16 lanes) ----
      {
        float mx[4], sum[4];
        #pragma unroll
        for (int r=0;r<4;r++) {
          mx[r] = fmaxf(fmaxf(val[0][r], val[1][r]), fmaxf(val[2][r], val[3][r]));
          #pragma unroll
          for (int m = 1; m < 16; m <<= 1) mx[r] = fmaxf(mx[r], __shfl_xor(mx[r], m));
        }
        #pragma unroll
        for (int nt=0;nt<4;nt++)
          #pragma unroll
          for (int r=0;r<4;r++) val[nt][r] = __expf(val[nt][r] - mx[r]);
        #pragma unroll
        for (int r=0;r<4;r++) {
          sum[r] = val[0][r] + val[1][r] + val[2][r] + val[3][r];
          #pragma unroll
          for (int m = 1; m < 16; m <<= 1) sum[r] += __shfl_xor(sum[r], m);
          sum[r] = 1.f / sum[r];
        }
        #pragma unroll
        for (int nt=0;nt<4;nt++)
          #pragma unroll
          for (int r=0;r<4;r++)
            P[(wave*16 + quad*4 + r)*72 + nt*16 + ln15] = (bfr)(val[nt][r]*sum[r]);
      }
      __syncthreads();
      // ---- PV: wave owns rows wave*16..+15, d-tiles nt=0..1 ----
      #pragma unroll
      for (int nt = 0; nt < 2; nt++) {
        f32x4 c = ZERO4;
        #pragma unroll
        for (int k0 = 0; k0 < 64; k0 += 32) {
          bf8 ap = *(const bf8*)&P[(wave*16 + ln15)*72 + k0 + quad*8];
          bf8 bv = *(const bf8*)&vT[(hl*32 + nt*16 + ln15)*72 + k0 + quad*8];
          c = MFMA16(ap, bv, c);
        }
        #pragma unroll
        for (int r=0;r<4;r++)
          ov[(wave*16 + quad*4 + r)*36 + nt*16 + ln15] = (bfr)c[r];
      }
      __syncthreads();
      // ---- proj K-step for this head (K=32 chunk at head*32) ----
      {
        bf8 afr[4];
        #pragma unroll
        for (int mt=0;mt<4;mt++)
          afr[mt] = *(const bf8*)&ov[(mt*16+ln15)*36 + quad*8];
        #pragma unroll
        for (int j=0;j<3;j++) {
          int col = (wave*3+j)*16 + ln15;
          bf8 bw = *(const bf8*)&projwT[(size_t)col*192 + head*32 + quad*8];
          #pragma unroll
          for (int mt=0;mt<4;mt++) accp[j][mt] = MFMA16(afr[mt], bw, accp[j][mt]);
        }
      }
    }
  }

  // ---- epilogue: bias -> pj overlay -> coalesced residual+scatter ----
  #pragma unroll
  for (int j=0;j<3;j++) {
    int col = (wave*3+j)*16 + ln15;
    float pb = projb[col];
    #pragma unroll
    for (int mt=0;mt<4;mt++)
      #pragma unroll
      for (int r=0;r<4;r++)
        pj[(mt*16 + quad*4 + r)*196 + col] = accp[j][mt][r] + pb;
  }
  __syncthreads();
  for (int idx = tid; idx < N_*C_; idx += 256) {
    int n = idx / C_, c = idx % C_;
    size_t gr = (size_t)srows[n]*C_ + c;
    out[gr] = x[gr] + pj[n*196 + c];
  }
}

// ================= Kernel 2: LN2 + fc1 + GELU + fc2 + residual, 64 rows/block ================
// M=64: each weight fragment loaded once per block now feeds 4 row-tiles (halves L2
// weight traffic vs M=32: 1.85 GB -> 0.93 GB per dispatch).
// LDS: ts[64][200] bf16 (25600) + hidc[64][200] bf16 (25600) = 51200 B -> 3 blocks/CU.
// st f32[64][196] (50176) overlays ts+hidc after last use.
#define SM2_TS  0
#define SM2_HID 25600
#define SM2_TOT 51200

__global__ __launch_bounds__(256, 3) void k_mlp(
    float* __restrict__ y,
    const float* __restrict__ n2w, const float* __restrict__ n2b,
    const bfr* __restrict__ wsp,
    const float* __restrict__ b1, const float* __restrict__ b2)
{
  __shared__ char smem[SM2_TOT];
  bfr*   ts   = (bfr*)(smem + SM2_TS);
  bfr*   hidc = (bfr*)(smem + SM2_HID);
  float* st   = (float*)smem;       // overlay after ts/hidc dead

  const f32x4 ZERO4 = {0.f, 0.f, 0.f, 0.f};

  int r0 = blockIdx.x * 64;
  int tid = threadIdx.x;
  int lane = tid & 63, wave = tid >> 6;
  int ln15 = lane & 15, quad = lane >> 4;

  // ---- LN2 (one row per wave iteration) ----
  for (int r = wave; r < 64; r += 4) {
    const float* yr = y + (size_t)(r0 + r)*C_;
    float v0 = yr[lane], v1 = yr[lane+64], v2 = yr[lane+128];
    float s = v0+v1+v2, q = v0*v0+v1*v1+v2*v2;
    #pragma unroll
    for (int m = 32; m; m >>= 1) { s += __shfl_xor(s, m); q += __shfl_xor(q, m); }
    float mu = s*(1.f/C_), var = q*(1.f/C_) - mu*mu;
    float rs = rsqrtf(var + 1e-5f);
    ts[r*HSP + lane]     = (bfr)((v0-mu)*rs*n2w[lane]     + n2b[lane]);
    ts[r*HSP + lane+64]  = (bfr)((v1-mu)*rs*n2w[lane+64]  + n2b[lane+64]);
    ts[r*HSP + lane+128] = (bfr)((v2-mu)*rs*n2w[lane+128] + n2b[lane+128]);
  }
  __syncthreads();

  const bfr* w1T = wsp + OW1;
  const bfr* w2T = wsp + OW2;

  f32x4 accp[3][4];   // fc2 accumulators, persist across chunks
  #pragma unroll
  for (int j=0;j<3;j++)
    #pragma unroll
    for (int mt=0;mt<4;mt++) accp[j][mt] = ZERO4;

  for (int c = 0; c < 4; c++) {
    // ---- fc1 chunk: M=64, N=192 (cols c*192..+191), K=192 ----
    {
      f32x4 acc[3][4];
      #pragma unroll
      for (int j=0;j<3;j++)
        #pragma unroll
        for (int mt=0;mt<4;mt++) acc[j][mt] = ZERO4;
      for (int k0 = 0; k0 < C_; k0 += 32) {
        bf8 afr[4];
        #pragma unroll
        for (int mt=0;mt<4;mt++)
          afr[mt] = *(const bf8*)&ts[(mt*16+ln15)*HSP + k0 + quad*8];
        #pragma unroll
        for (int j=0;j<3;j++) {
          int gcol = (c*12 + wave*3 + j)*16 + ln15;
          bf8 bw = *(const bf8*)&w1T[(size_t)gcol*192 + k0 + quad*8];
          #pragma unroll
          for (int mt=0;mt<4;mt++) acc[j][mt] = MFMA16(afr[mt], bw, acc[j][mt]);
        }
      }
      // GELU (tanh-form: g*sigmoid(1.59576912*g + 0.07135482*g^3), |err|<3e-4 << bf16 lsb)
      #pragma unroll
      for (int j=0;j<3;j++) {
        int colc = (wave*3 + j)*16 + ln15;
        float bb = b1[c*192 + colc];
        #pragma unroll
        for (int mt=0;mt<4;mt++)
          #pragma unroll
          for (int r=0;r<4;r++) {
            int row = mt*16 + quad*4 + r;
            float g = acc[j][mt][r] + bb;
            float u = g*(1.5957691216f + 0.0713548170f*g*g);
            hidc[row*HSP + colc] = (bfr)(g / (1.f + __expf(-u)));
          }
      }
    }
    __syncthreads();
    // ---- fc2 partial: M=64, N=192, K=192 (k-range c*192..+191) ----
    for (int k0 = 0; k0 < 192; k0 += 32) {
      bf8 afr[4];
      #pragma unroll
      for (int mt=0;mt<4;mt++)
        afr[mt] = *(const bf8*)&hidc[(mt*16+ln15)*HSP + k0 + quad*8];
      #pragma unroll
      for (int j=0;j<3;j++) {
        int col = (wave*3+j)*16 + ln15;
        bf8 bw = *(const bf8*)&w2T[(size_t)col*768 + c*192 + k0 + quad*8];
        #pragma unroll
        for (int mt=0;mt<4;mt++) accp[j][mt] = MFMA16(afr[mt], bw, accp[j][mt]);
      }
    }
    __syncthreads();   // hidc reads done before next chunk's writes (or st overlay)
  }

  // ---- epilogue: bias -> st overlay (over ts/hidc, both dead) ----
  #pragma unroll
  for (int j=0;j<3;j++) {
    int col = (wave*3+j)*16 + ln15;
    float bb = b2[col];
    #pragma unroll
    for (int mt=0;mt<4;mt++)
      #pragma unroll
      for (int r=0;r<4;r++) {
        int row = mt*16 + quad*4 + r;
        st[row*196 + col] = accp[j][mt][r] + bb;
      }
  }
  __syncthreads();
  // residual, coalesced, in-place
  for (int idx = tid; idx < 64*C_; idx += 256) {
    int r = idx / C_, c = idx % C_;
    size_t gr = (size_t)(r0 + r)*C_ + c;
    y[gr] = y[gr] + st[r*196 + c];
  }
}

extern "C" void kernel_launch(void* const* d_in, const int* in_sizes, int n_in,
                              void* d_out, int out_size, void* d_ws, size_t ws_size,
                              hipStream_t stream) {
  const float* x     = (const float*)d_in[0];
  const float* n1w   = (const float*)d_in[1];
  const float* n1b   = (const float*)d_in[2];
  const float* qkvw  = (const float*)d_in[3];
  const float* qkvb  = (const float*)d_in[4];
  const float* btab  = (const float*)d_in[5];
  const float* projw = (const float*)d_in[6];
  const float* projb = (const float*)d_in[7];
  const float* n2w   = (const float*)d_in[8];
  const float* n2b   = (const float*)d_in[9];
  const float* w1    = (const float*)d_in[10];
  const float* b1    = (const float*)d_in[11];
  const float* w2    = (const float*)d_in[12];
  const float* b2    = (const float*)d_in[13];
  const float* mask  = (const float*)d_in[14];
  const int*   rel   = (const int*)d_in[15];
  float* out = (float*)d_out;
  bfr*   wsp = (bfr*)d_ws;   // (442368 + 1572864) * 2 B ~= 4.03 MB

  k_prep<<<(WTOT+255)/256, 256, 0, stream>>>(qkvw, projw, w1, w2, wsp);
  k_prep2<<<(BMTOT+255)/256, 256, 0, stream>>>(btab, rel, mask, wsp + OBM);
  k_attn<<<NWIN, 256, 0, stream>>>(x, n1w, n1b, wsp, qkvb, projb, out);
  k_mlp<<<ROWS/64, 256, 0, stream>>>(out, n2w, n2b, wsp, b1, b2);
}

// Round 3
// 535.647 us; speedup vs baseline: 1.2331x; 1.0678x over previous
//
#include <hip/hip_runtime.h>
#include <math.h>

#define B_    32
#define HH    56
#define WW_   56
#define C_    192
#define WS_   7
#define SHIFT_ 3
#define HEADS_ 6
#define DH    32
#define N_    49
#define NWIN  2048
#define ROWS  100352
#define HID_  768
#define QKVN  576

typedef __bf16 bfr;
typedef __bf16 bf8 __attribute__((ext_vector_type(8)));
typedef __bf16 bf4 __attribute__((ext_vector_type(4)));
typedef float  f32x4 __attribute__((ext_vector_type(4)));

#define MFMA16(a,b,c) __builtin_amdgcn_mfma_f32_16x16x32_bf16(a,b,c,0,0,0)

// ---- ws layout (bf16 elements) ----
#define OQW   0         // qkvwT [576][192]
#define OPW   110592    // projwT[192][192]
#define OW1   147456    // w1T   [768][192]
#define OW2   294912    // w2T   [192][768]
#define OBM   442368    // bmask [6][64][64col][64row]  TRANSPOSED (bias+mask, pads=-1e30)
#define WTOT  442368
#define BMTOT 1572864   // 6*64*64*64

// ================= k_prep: transpose + fp32->bf16 all weights =================
__global__ __launch_bounds__(256) void k_prep(
    const float* __restrict__ qkvw, const float* __restrict__ projw,
    const float* __restrict__ w1,   const float* __restrict__ w2,
    bfr* __restrict__ wsp)
{
  int idx = blockIdx.x*256 + threadIdx.x;
  if (idx >= WTOT) return;
  if (idx < OPW)      { int i=idx;      int n=i/192, k=i%192; wsp[idx] = (bfr)qkvw[k*QKVN + n]; }
  else if (idx < OW1) { int i=idx-OPW;  int n=i/192, k=i%192; wsp[idx] = (bfr)projw[k*C_ + n]; }
  else if (idx < OW2) { int i=idx-OW1;  int n=i/192, k=i%192; wsp[idx] = (bfr)w1[k*HID_ + n]; }
  else                { int i=idx-OW2;  int n=i/768, k=i%768; wsp[idx] = (bfr)w2[k*C_ + n]; }
}

// ====== k_prep2: bmask[head][wi][col64][row64] = bias + mask, TRANSPOSED (pads -1e30) ======
__global__ __launch_bounds__(256) void k_prep2(
    const float* __restrict__ btab, const int* __restrict__ rel,
    const float* __restrict__ mask, bfr* __restrict__ bm)
{
  int idx = blockIdx.x*256 + threadIdx.x;   // [head][wi][col][row] -- row fastest
  if (idx >= BMTOT) return;
  int row = idx & 63, col = (idx>>6) & 63, wi = (idx>>12) & 63, head = idx>>18;
  float v = -1e30f;
  if (row < N_ && col < N_) {
    int e = row*N_ + col;
    v = btab[rel[e]*HEADS_ + head] + mask[(size_t)wi*N_*N_ + e];
  }
  bm[idx] = (bfr)v;
}

// ================= Kernel 1: LN1+shift+QKV+attn+proj+residual, head-pair fused ============
// LDS (bytes):
#define SM_HS 0        // bfr hs[64][200]          25600  (LN'd input, persists)
#define SM_QS 25600    // bfr qs[2][64][36]         9216
#define SM_KS 34816    // bfr ks[2][64][36]         9216
#define SM_VT 44032    // bfr vT[2][32][72]         9216
#define SM_P  53248    // bfr P[64][72]             9216  (wave-row-local scratch)
#define SM_OV 62464    // bfr ov2[64][72]           9216  (both heads: [row][hl*36+d])
#define SM_SR 71680    // int srows[64]              256
#define SM1_TOT 71936
#define HSP 200

__global__ __launch_bounds__(256, 2) void k_attn(
    const float* __restrict__ x,
    const float* __restrict__ n1w, const float* __restrict__ n1b,
    const bfr*   __restrict__ wsp,
    const float* __restrict__ qkvb,
    const float* __restrict__ projb,
    float* __restrict__ out)
{
  __shared__ char smem[SM1_TOT];
  bfr*   hs    = (bfr*)(smem + SM_HS);
  bfr*   qs    = (bfr*)(smem + SM_QS);
  bfr*   ks    = (bfr*)(smem + SM_KS);
  bfr*   vT    = (bfr*)(smem + SM_VT);
  bfr*   P     = (bfr*)(smem + SM_P);
  bfr*   ov2   = (bfr*)(smem + SM_OV);
  int*   srows = (int*)(smem + SM_SR);
  float* pj    = (float*)smem;   // overlay [64][196] fp32 = 50176 B over hs/qs/ks/vT

  const f32x4 ZERO4 = {0.f, 0.f, 0.f, 0.f};

  int win  = blockIdx.x;
  int tid  = threadIdx.x;
  int lane = tid & 63, wave = tid >> 6;
  int ln15 = lane & 15, quad = lane >> 4;
  int wi   = win & 63;

  // ---- srows + zero hs pad rows (49..63 only; rows 0..48 fully overwritten by LN) ----
  if (tid < N_) {
    int bb = win >> 6;
    int wh = wi >> 3, ww = wi & 7;
    int th = tid / WS_, tw = tid % WS_;
    int sh = wh*WS_ + th + SHIFT_; if (sh >= HH) sh -= HH;
    int sw = ww*WS_ + tw + SHIFT_; if (sw >= WW_) sw -= WW_;
    srows[tid] = bb*HH*WW_ + sh*WW_ + sw;
  }
  {
    int* hz = (int*)(hs + 49*HSP);
    for (int i = tid; i < 15*HSP/2; i += 256) hz[i] = 0;
  }
  __syncthreads();
  // ---- LN1 -> hs ----
  for (int r = wave; r < N_; r += 4) {
    const float* xr = x + (size_t)srows[r]*C_;
    float v0 = xr[lane], v1 = xr[lane+64], v2 = xr[lane+128];
    float s = v0+v1+v2, q = v0*v0+v1*v1+v2*v2;
    #pragma unroll
    for (int m = 32; m; m >>= 1) { s += __shfl_xor(s, m); q += __shfl_xor(q, m); }
    float mu = s*(1.f/C_), var = q*(1.f/C_) - mu*mu;
    float rs = rsqrtf(var + 1e-5f);
    hs[r*HSP + lane]     = (bfr)((v0-mu)*rs*n1w[lane]     + n1b[lane]);
    hs[r*HSP + lane+64]  = (bfr)((v1-mu)*rs*n1w[lane+64]  + n1b[lane+64]);
    hs[r*HSP + lane+128] = (bfr)((v2-mu)*rs*n1w[lane+128] + n1b[lane+128]);
  }
  __syncthreads();

  const bfr* qkvwT  = wsp + OQW;
  const bfr* projwT = wsp + OPW;
  const bfr* bmask  = wsp + OBM;

  f32x4 accp[3][4];   // proj accumulators, persist across pairs
  #pragma unroll
  for (int j=0;j<3;j++)
    #pragma unroll
    for (int mt=0;mt<4;mt++) accp[j][mt] = ZERO4;

  for (int pair = 0; pair < 3; pair++) {
    // ---- QKV for this pair: wave handles col-tile (wave) of q(j=0),k(j=1),v(j=2) ----
    {
      f32x4 acc[3][4];
      #pragma unroll
      for (int j=0;j<3;j++)
        #pragma unroll
        for (int mt=0;mt<4;mt++) acc[j][mt] = ZERO4;
      for (int k0 = 0; k0 < C_; k0 += 32) {
        bf8 afr[4];
        #pragma unroll
        for (int mt=0;mt<4;mt++)
          afr[mt] = *(const bf8*)&hs[(mt*16+ln15)*HSP + k0 + quad*8];
        #pragma unroll
        for (int j=0;j<3;j++) {
          int colg = j*192 + pair*64 + wave*16 + ln15;
          bf8 bw = *(const bf8*)&qkvwT[(size_t)colg*192 + k0 + quad*8];
          #pragma unroll
          for (int mt=0;mt<4;mt++) acc[j][mt] = MFMA16(afr[mt], bw, acc[j][mt]);
        }
      }
      int colp = wave*16 + ln15;         // within-pair col 0..63
      int hl = colp >> 5, d = colp & 31;
      #pragma unroll
      for (int j=0;j<3;j++) {
        float bias = qkvb[j*192 + pair*64 + colp];
        #pragma unroll
        for (int mt=0;mt<4;mt++)
          #pragma unroll
          for (int r=0;r<4;r++) {
            int row = mt*16 + quad*4 + r;
            float vv = acc[j][mt][r] + bias;
            if (j == 0)      qs[(hl*64+row)*36 + d] = (bfr)(vv*0.17677669529663689f);
            else if (j == 1) ks[(hl*64+row)*36 + d] = (bfr)vv;
            else             vT[(hl*32+d)*72 + row] = (bfr)vv;
          }
      }
    }
    __syncthreads();

    // ---- QK^T for BOTH heads, bias+mask as MFMA C-init (transposed bmask, 8B loads) ----
    float val[2][4][4];   // [hl][nt][r]
    #pragma unroll
    for (int hl = 0; hl < 2; hl++) {
      int head = pair*2 + hl;
      const bfr* bmh = bmask + (((size_t)head*64 + wi) << 12);  // [col64][row64]
      bf8 aq = *(const bf8*)&qs[(hl*64 + wave*16 + ln15)*36 + quad*8];
      #pragma unroll
      for (int nt = 0; nt < 4; nt++) {
        bf4 bm4 = *(const bf4*)&bmh[(nt*16 + ln15)*64 + wave*16 + quad*4];
        f32x4 c;
        c[0] = (float)bm4[0]; c[1] = (float)bm4[1];
        c[2] = (float)bm4[2]; c[3] = (float)bm4[3];
        bf8 bk = *(const bf8*)&ks[(hl*64 + nt*16 + ln15)*36 + quad*8];
        c = MFMA16(aq, bk, c);
        #pragma unroll
        for (int r=0;r<4;r++) val[hl][nt][r] = c[r];
      }
    }

    // ---- per head: register softmax + P (wave-row-local, NO barrier) + PV + ov2 ----
    #pragma unroll
    for (int hl = 0; hl < 2; hl++) {
      float mx[4], sum[4];
      #pragma unroll
      for (int r=0;r<4;r++) {
        mx[r] = fmaxf(fmaxf(val[hl][0][r], val[hl][1][r]), fmaxf(val[hl][2][r], val[hl][3][r]));
        #pragma unroll
        for (int m = 1; m < 16; m <<= 1) mx[r] = fmaxf(mx[r], __shfl_xor(mx[r], m));
      }
      #pragma unroll
      for (int nt=0;nt<4;nt++)
        #pragma unroll
        for (int r=0;r<4;r++) val[hl][nt][r] = __expf(val[hl][nt][r] - mx[r]);
      #pragma unroll
      for (int r=0;r<4;r++) {
        sum[r] = val[hl][0][r] + val[hl][1][r] + val[hl][2][r] + val[hl][3][r];
        #pragma unroll
        for (int m = 1; m < 16; m <<= 1) sum[r] += __shfl_xor(sum[r], m);
        sum[r] = 1.f / sum[r];
      }
      #pragma unroll
      for (int nt=0;nt<4;nt++)
        #pragma unroll
        for (int r=0;r<4;r++)
          P[(wave*16 + quad*4 + r)*72 + nt*16 + ln15] = (bfr)(val[hl][nt][r]*sum[r]);
      // PV: wave reads ONLY its own P rows (wave*16..+15) -> in-wave lgkmcnt dep, no barrier
      #pragma unroll
      for (int nt = 0; nt < 2; nt++) {
        f32x4 c = ZERO4;
        #pragma unroll
        for (int k0 = 0; k0 < 64; k0 += 32) {
          bf8 ap = *(const bf8*)&P[(wave*16 + ln15)*72 + k0 + quad*8];
          bf8 bv = *(const bf8*)&vT[(hl*32 + nt*16 + ln15)*72 + k0 + quad*8];
          c = MFMA16(ap, bv, c);
        }
        #pragma unroll
        for (int r=0;r<4;r++)
          ov2[(wave*16 + quad*4 + r)*72 + hl*36 + nt*16 + ln15] = (bfr)c[r];
      }
    }
    __syncthreads();

    // ---- proj K-step for this pair (K=64: both heads) ----
    #pragma unroll
    for (int hl = 0; hl < 2; hl++) {
      int head = pair*2 + hl;
      bf8 afr[4];
      #pragma unroll
      for (int mt=0;mt<4;mt++)
        afr[mt] = *(const bf8*)&ov2[(mt*16+ln15)*72 + hl*36 + quad*8];
      #pragma unroll
      for (int j=0;j<3;j++) {
        int col = (wave*3+j)*16 + ln15;
        bf8 bw = *(const bf8*)&projwT[(size_t)col*192 + head*32 + quad*8];
        #pragma unroll
        for (int mt=0;mt<4;mt++) accp[j][mt] = MFMA16(afr[mt], bw, accp[j][mt]);
      }
    }
    // no barrier: next pair's QKV writes qs/ks/vT, disjoint from ov2/weights read here;
    // all qs/ks/vT READS of this pair completed before the ov2 barrier above.
  }

  // ---- epilogue: bias -> pj overlay -> coalesced residual+scatter ----
  __syncthreads();   // all waves past last proj (ov2 reads) before pj overlays hs..vT
  #pragma unroll
  for (int j=0;j<3;j++) {
    int col = (wave*3+j)*16 + ln15;
    float pb = projb[col];
    #pragma unroll
    for (int mt=0;mt<4;mt++)
      #pragma unroll
      for (int r=0;r<4;r++)
        pj[(mt*16 + quad*4 + r)*196 + col] = accp[j][mt][r] + pb;
  }
  __syncthreads();
  for (int idx = tid; idx < N_*C_; idx += 256) {
    int n = idx / C_, c = idx % C_;
    size_t gr = (size_t)srows[n]*C_ + c;
    out[gr] = x[gr] + pj[n*196 + c];
  }
}

// ================= Kernel 2: LN2 + fc1 + GELU + fc2 + residual, 64 rows/block ================
// LDS: ts[64][200] bf16 (25600) + hidc[64][200] bf16 (25600) = 51200 B -> 3 blocks/CU.
// st f32[64][196] (50176) overlays ts+hidc after last use.
#define SM2_TS  0
#define SM2_HID 25600
#define SM2_TOT 51200

__global__ __launch_bounds__(256, 3) void k_mlp(
    float* __restrict__ y,
    const float* __restrict__ n2w, const float* __restrict__ n2b,
    const bfr* __restrict__ wsp,
    const float* __restrict__ b1, const float* __restrict__ b2)
{
  __shared__ char smem[SM2_TOT];
  bfr*   ts   = (bfr*)(smem + SM2_TS);
  bfr*   hidc = (bfr*)(smem + SM2_HID);
  float* st   = (float*)smem;       // overlay after ts/hidc dead

  const f32x4 ZERO4 = {0.f, 0.f, 0.f, 0.f};

  int r0 = blockIdx.x * 64;
  int tid = threadIdx.x;
  int lane = tid & 63, wave = tid >> 6;
  int ln15 = lane & 15, quad = lane >> 4;

  // ---- LN2 ----
  for (int r = wave; r < 64; r += 4) {
    const float* yr = y + (size_t)(r0 + r)*C_;
    float v0 = yr[lane], v1 = yr[lane+64], v2 = yr[lane+128];
    float s = v0+v1+v2, q = v0*v0+v1*v1+v2*v2;
    #pragma unroll
    for (int m = 32; m; m >>= 1) { s += __shfl_xor(s, m); q += __shfl_xor(q, m); }
    float mu = s*(1.f/C_), var = q*(1.f/C_) - mu*mu;
    float rs = rsqrtf(var + 1e-5f);
    ts[r*HSP + lane]     = (bfr)((v0-mu)*rs*n2w[lane]     + n2b[lane]);
    ts[r*HSP + lane+64]  = (bfr)((v1-mu)*rs*n2w[lane+64]  + n2b[lane+64]);
    ts[r*HSP + lane+128] = (bfr)((v2-mu)*rs*n2w[lane+128] + n2b[lane+128]);
  }
  __syncthreads();

  const bfr* w1T = wsp + OW1;
  const bfr* w2T = wsp + OW2;

  f32x4 accp[3][4];   // fc2 accumulators, persist across chunks
  #pragma unroll
  for (int j=0;j<3;j++)
    #pragma unroll
    for (int mt=0;mt<4;mt++) accp[j][mt] = ZERO4;

  for (int c = 0; c < 4; c++) {
    // ---- fc1 chunk: M=64, N=192 (cols c*192..+191), K=192 ----
    {
      f32x4 acc[3][4];
      #pragma unroll
      for (int j=0;j<3;j++)
        #pragma unroll
        for (int mt=0;mt<4;mt++) acc[j][mt] = ZERO4;
      for (int k0 = 0; k0 < C_; k0 += 32) {
        bf8 afr[4];
        #pragma unroll
        for (int mt=0;mt<4;mt++)
          afr[mt] = *(const bf8*)&ts[(mt*16+ln15)*HSP + k0 + quad*8];
        #pragma unroll
        for (int j=0;j<3;j++) {
          int gcol = (c*12 + wave*3 + j)*16 + ln15;
          bf8 bw = *(const bf8*)&w1T[(size_t)gcol*192 + k0 + quad*8];
          #pragma unroll
          for (int mt=0;mt<4;mt++) acc[j][mt] = MFMA16(afr[mt], bw, acc[j][mt]);
        }
      }
      // GELU (tanh-form: g*sigmoid(1.59576912*g + 0.07135482*g^3), |err|<3e-4 << bf16 lsb)
      #pragma unroll
      for (int j=0;j<3;j++) {
        int colc = (wave*3 + j)*16 + ln15;
        float bb = b1[c*192 + colc];
        #pragma unroll
        for (int mt=0;mt<4;mt++)
          #pragma unroll
          for (int r=0;r<4;r++) {
            int row = mt*16 + quad*4 + r;
            float g = acc[j][mt][r] + bb;
            float u = g*(1.5957691216f + 0.0713548170f*g*g);
            hidc[row*HSP + colc] = (bfr)(g / (1.f + __expf(-u)));
          }
      }
    }
    __syncthreads();
    // ---- fc2 partial: M=64, N=192, K=192 (k-range c*192..+191) ----
    for (int k0 = 0; k0 < 192; k0 += 32) {
      bf8 afr[4];
      #pragma unroll
      for (int mt=0;mt<4;mt++)
        afr[mt] = *(const bf8*)&hidc[(mt*16+ln15)*HSP + k0 + quad*8];
      #pragma unroll
      for (int j=0;j<3;j++) {
        int col = (wave*3+j)*16 + ln15;
        bf8 bw = *(const bf8*)&w2T[(size_t)col*768 + c*192 + k0 + quad*8];
        #pragma unroll
        for (int mt=0;mt<4;mt++) accp[j][mt] = MFMA16(afr[mt], bw, accp[j][mt]);
      }
    }
    __syncthreads();   // hidc reads done before next chunk's writes (or st overlay)
  }

  // ---- epilogue: bias -> st overlay (over ts/hidc, both dead) ----
  #pragma unroll
  for (int j=0;j<3;j++) {
    int col = (wave*3+j)*16 + ln15;
    float bb = b2[col];
    #pragma unroll
    for (int mt=0;mt<4;mt++)
      #pragma unroll
      for (int r=0;r<4;r++) {
        int row = mt*16 + quad*4 + r;
        st[row*196 + col] = accp[j][mt][r] + bb;
      }
  }
  __syncthreads();
  // residual, coalesced, in-place
  for (int idx = tid; idx < 64*C_; idx += 256) {
    int r = idx / C_, c = idx % C_;
    size_t gr = (size_t)(r0 + r)*C_ + c;
    y[gr] = y[gr] + st[r*196 + c];
  }
}

extern "C" void kernel_launch(void* const* d_in, const int* in_sizes, int n_in,
                              void* d_out, int out_size, void* d_ws, size_t ws_size,
                              hipStream_t stream) {
  const float* x     = (const float*)d_in[0];
  const float* n1w   = (const float*)d_in[1];
  const float* n1b   = (const float*)d_in[2];
  const float* qkvw  = (const float*)d_in[3];
  const float* qkvb  = (const float*)d_in[4];
  const float* btab  = (const float*)d_in[5];
  const float* projw = (const float*)d_in[6];
  const float* projb = (const float*)d_in[7];
  const float* n2w   = (const float*)d_in[8];
  const float* n2b   = (const float*)d_in[9];
  const float* w1    = (const float*)d_in[10];
  const float* b1    = (const float*)d_in[11];
  const float* w2    = (const float*)d_in[12];
  const float* b2    = (const float*)d_in[13];
  const float* mask  = (const float*)d_in[14];
  const int*   rel   = (const int*)d_in[15];
  float* out = (float*)d_out;
  bfr*   wsp = (bfr*)d_ws;   // (442368 + 1572864) * 2 B ~= 4.03 MB

  k_prep<<<(WTOT+255)/256, 256, 0, stream>>>(qkvw, projw, w1, w2, wsp);
  k_prep2<<<(BMTOT+255)/256, 256, 0, stream>>>(btab, rel, mask, wsp + OBM);
  k_attn<<<NWIN, 256, 0, stream>>>(x, n1w, n1b, wsp, qkvb, projb, out);
  k_mlp<<<ROWS/64, 256, 0, stream>>>(out, n2w, n2b, wsp, b1, b2);
}

// Round 4
// 522.337 us; speedup vs baseline: 1.2645x; 1.0255x over previous
//
#include <hip/hip_runtime.h>
#include <math.h>

#define B_    32
#define HH    56
#define WW_   56
#define C_    192
#define WS_   7
#define SHIFT_ 3
#define HEADS_ 6
#define DH    32
#define N_    49
#define NWIN  2048
#define ROWS  100352
#define HID_  768
#define QKVN  576

typedef __bf16 bfr;
typedef __bf16 bf8 __attribute__((ext_vector_type(8)));
typedef __bf16 bf4 __attribute__((ext_vector_type(4)));
typedef float  f32x4 __attribute__((ext_vector_type(4)));

#define MFMA16(a,b,c) __builtin_amdgcn_mfma_f32_16x16x32_bf16(a,b,c,0,0,0)

// ---- ws layout (bf16 elements) ----
#define OQW   0         // qkvwT [576][192]
#define OPW   110592    // projwT[192][192]
#define OW1   147456    // w1T   [768][192]
#define OW2   294912    // w2T   [192][768]
#define OBM   442368    // bmask [6][64][64col][64row]  TRANSPOSED (bias+mask, pads=-1e30)
#define WTOT  442368
#define BMTOT 1572864   // 6*64*64*64

// ================= k_prep: transpose + fp32->bf16 all weights =================
__global__ __launch_bounds__(256) void k_prep(
    const float* __restrict__ qkvw, const float* __restrict__ projw,
    const float* __restrict__ w1,   const float* __restrict__ w2,
    bfr* __restrict__ wsp)
{
  int idx = blockIdx.x*256 + threadIdx.x;
  if (idx >= WTOT) return;
  if (idx < OPW)      { int i=idx;      int n=i/192, k=i%192; wsp[idx] = (bfr)qkvw[k*QKVN + n]; }
  else if (idx < OW1) { int i=idx-OPW;  int n=i/192, k=i%192; wsp[idx] = (bfr)projw[k*C_ + n]; }
  else if (idx < OW2) { int i=idx-OW1;  int n=i/192, k=i%192; wsp[idx] = (bfr)w1[k*HID_ + n]; }
  else                { int i=idx-OW2;  int n=i/768, k=i%768; wsp[idx] = (bfr)w2[k*C_ + n]; }
}

// ====== k_prep2: bmask[head][wi][col64][row64] = bias + mask, TRANSPOSED (pads -1e30) ======
__global__ __launch_bounds__(256) void k_prep2(
    const float* __restrict__ btab, const int* __restrict__ rel,
    const float* __restrict__ mask, bfr* __restrict__ bm)
{
  int idx = blockIdx.x*256 + threadIdx.x;   // [head][wi][col][row] -- row fastest
  if (idx >= BMTOT) return;
  int row = idx & 63, col = (idx>>6) & 63, wi = (idx>>12) & 63, head = idx>>18;
  float v = -1e30f;
  if (row < N_ && col < N_) {
    int e = row*N_ + col;
    v = btab[rel[e]*HEADS_ + head] + mask[(size_t)wi*N_*N_ + e];
  }
  bm[idx] = (bfr)v;
}

// ================= Kernel 1: LN1+shift+QKV+attn+proj+residual, head-pair fused ============
// LDS (bytes):
#define SM_HS 0        // bfr hs[64][200]          25600  (LN'd input, persists)
#define SM_QS 25600    // bfr qs[2][64][36]         9216
#define SM_KS 34816    // bfr ks[2][64][36]         9216
#define SM_VT 44032    // bfr vT[2][32][72]         9216
#define SM_P  53248    // bfr P[64][72]             9216  (wave-row-local scratch)
#define SM_OV 62464    // bfr ov2[64][72]           9216  (both heads: [row][hl*36+d])
#define SM_SR 71680    // int srows[64]              256
#define SM1_TOT 71936
#define HSP 200

__global__ __launch_bounds__(256, 2) void k_attn(
    const float* __restrict__ x,
    const float* __restrict__ n1w, const float* __restrict__ n1b,
    const bfr*   __restrict__ wsp,
    const float* __restrict__ qkvb,
    const float* __restrict__ projb,
    float* __restrict__ out)
{
  __shared__ char smem[SM1_TOT];
  bfr*   hs    = (bfr*)(smem + SM_HS);
  bfr*   qs    = (bfr*)(smem + SM_QS);
  bfr*   ks    = (bfr*)(smem + SM_KS);
  bfr*   vT    = (bfr*)(smem + SM_VT);
  bfr*   P     = (bfr*)(smem + SM_P);
  bfr*   ov2   = (bfr*)(smem + SM_OV);
  int*   srows = (int*)(smem + SM_SR);
  float* pj    = (float*)smem;   // overlay [64][196] fp32 = 50176 B over hs/qs/ks/vT

  const f32x4 ZERO4 = {0.f, 0.f, 0.f, 0.f};

  int win  = blockIdx.x;
  int tid  = threadIdx.x;
  int lane = tid & 63, wave = tid >> 6;
  int ln15 = lane & 15, quad = lane >> 4;
  int wi   = win & 63;

  // ---- srows + zero hs pad rows (49..63 only) ----
  if (tid < N_) {
    int bb = win >> 6;
    int wh = wi >> 3, ww = wi & 7;
    int th = tid / WS_, tw = tid % WS_;
    int sh = wh*WS_ + th + SHIFT_; if (sh >= HH) sh -= HH;
    int sw = ww*WS_ + tw + SHIFT_; if (sw >= WW_) sw -= WW_;
    srows[tid] = bb*HH*WW_ + sh*WW_ + sw;
  }
  {
    int* hz = (int*)(hs + 49*HSP);
    for (int i = tid; i < 15*HSP/2; i += 256) hz[i] = 0;
  }
  __syncthreads();
  // ---- LN1 -> hs ----
  for (int r = wave; r < N_; r += 4) {
    const float* xr = x + (size_t)srows[r]*C_;
    float v0 = xr[lane], v1 = xr[lane+64], v2 = xr[lane+128];
    float s = v0+v1+v2, q = v0*v0+v1*v1+v2*v2;
    #pragma unroll
    for (int m = 32; m; m >>= 1) { s += __shfl_xor(s, m); q += __shfl_xor(q, m); }
    float mu = s*(1.f/C_), var = q*(1.f/C_) - mu*mu;
    float rs = rsqrtf(var + 1e-5f);
    hs[r*HSP + lane]     = (bfr)((v0-mu)*rs*n1w[lane]     + n1b[lane]);
    hs[r*HSP + lane+64]  = (bfr)((v1-mu)*rs*n1w[lane+64]  + n1b[lane+64]);
    hs[r*HSP + lane+128] = (bfr)((v2-mu)*rs*n1w[lane+128] + n1b[lane+128]);
  }
  __syncthreads();

  const bfr* qkvwT  = wsp + OQW;
  const bfr* projwT = wsp + OPW;
  const bfr* bmask  = wsp + OBM;

  f32x4 accp[3][4];   // proj accumulators, persist across pairs
  #pragma unroll
  for (int j=0;j<3;j++)
    #pragma unroll
    for (int mt=0;mt<4;mt++) accp[j][mt] = ZERO4;

  for (int pair = 0; pair < 3; pair++) {
    // ---- QKV phase: burst-load all 18 weight fragments, then MFMA from LDS A ----
    {
      bf8 bw[3][6];
      float qb[3];
      #pragma unroll
      for (int j=0;j<3;j++) {
        const bfr* wb = qkvwT + (size_t)(j*192 + pair*64 + wave*16 + ln15)*192 + quad*8;
        #pragma unroll
        for (int kk=0;kk<6;kk++)
          bw[j][kk] = *(const bf8*)&wb[kk*32];
        qb[j] = qkvb[j*192 + pair*64 + wave*16 + ln15];
      }
      f32x4 acc[3][4];
      #pragma unroll
      for (int j=0;j<3;j++)
        #pragma unroll
        for (int mt=0;mt<4;mt++) acc[j][mt] = ZERO4;
      #pragma unroll
      for (int kk = 0; kk < 6; kk++) {
        bf8 afr[4];
        #pragma unroll
        for (int mt=0;mt<4;mt++)
          afr[mt] = *(const bf8*)&hs[(mt*16+ln15)*HSP + kk*32 + quad*8];
        #pragma unroll
        for (int j=0;j<3;j++)
          #pragma unroll
          for (int mt=0;mt<4;mt++) acc[j][mt] = MFMA16(afr[mt], bw[j][kk], acc[j][mt]);
      }
      int colp = wave*16 + ln15;         // within-pair col 0..63
      int hl = colp >> 5, d = colp & 31;
      #pragma unroll
      for (int j=0;j<3;j++) {
        #pragma unroll
        for (int mt=0;mt<4;mt++)
          #pragma unroll
          for (int r=0;r<4;r++) {
            int row = mt*16 + quad*4 + r;
            float vv = acc[j][mt][r] + qb[j];
            if (j == 0)      qs[(hl*64+row)*36 + d] = (bfr)(vv*0.17677669529663689f);
            else if (j == 1) ks[(hl*64+row)*36 + d] = (bfr)vv;
            else             vT[(hl*32+d)*72 + row] = (bfr)vv;
          }
      }
    }
    __syncthreads();

    // ---- bmask burst (both heads, 8x 8B loads) ----
    bf4 bm4[2][4];
    #pragma unroll
    for (int hl = 0; hl < 2; hl++) {
      const bfr* bmh = bmask + (((size_t)(pair*2+hl)*64 + wi) << 12);  // [col64][row64]
      #pragma unroll
      for (int nt = 0; nt < 4; nt++)
        bm4[hl][nt] = *(const bf4*)&bmh[(nt*16 + ln15)*64 + wave*16 + quad*4];
    }

    // ---- QK^T for BOTH heads, bias+mask as MFMA C-init ----
    float val[2][4][4];   // [hl][nt][r]
    #pragma unroll
    for (int hl = 0; hl < 2; hl++) {
      bf8 aq = *(const bf8*)&qs[(hl*64 + wave*16 + ln15)*36 + quad*8];
      #pragma unroll
      for (int nt = 0; nt < 4; nt++) {
        f32x4 c;
        c[0] = (float)bm4[hl][nt][0]; c[1] = (float)bm4[hl][nt][1];
        c[2] = (float)bm4[hl][nt][2]; c[3] = (float)bm4[hl][nt][3];
        bf8 bk = *(const bf8*)&ks[(hl*64 + nt*16 + ln15)*36 + quad*8];
        c = MFMA16(aq, bk, c);
        #pragma unroll
        for (int r=0;r<4;r++) val[hl][nt][r] = c[r];
      }
    }

    // ---- proj-weight burst (6x 16B): latency hides under softmax VALU ----
    bf8 pw[2][3];
    #pragma unroll
    for (int hl = 0; hl < 2; hl++)
      #pragma unroll
      for (int j = 0; j < 3; j++)
        pw[hl][j] = *(const bf8*)&projwT[(size_t)((wave*3+j)*16 + ln15)*192
                                         + (pair*2+hl)*32 + quad*8];

    // ---- per head: register softmax + P (wave-row-local, NO barrier) + PV -> ov2 ----
    #pragma unroll
    for (int hl = 0; hl < 2; hl++) {
      float mx[4], sum[4];
      #pragma unroll
      for (int r=0;r<4;r++) {
        mx[r] = fmaxf(fmaxf(val[hl][0][r], val[hl][1][r]), fmaxf(val[hl][2][r], val[hl][3][r]));
        #pragma unroll
        for (int m = 1; m < 16; m <<= 1) mx[r] = fmaxf(mx[r], __shfl_xor(mx[r], m));
      }
      #pragma unroll
      for (int nt=0;nt<4;nt++)
        #pragma unroll
        for (int r=0;r<4;r++) val[hl][nt][r] = __expf(val[hl][nt][r] - mx[r]);
      #pragma unroll
      for (int r=0;r<4;r++) {
        sum[r] = val[hl][0][r] + val[hl][1][r] + val[hl][2][r] + val[hl][3][r];
        #pragma unroll
        for (int m = 1; m < 16; m <<= 1) sum[r] += __shfl_xor(sum[r], m);
        sum[r] = 1.f / sum[r];
      }
      #pragma unroll
      for (int nt=0;nt<4;nt++)
        #pragma unroll
        for (int r=0;r<4;r++)
          P[(wave*16 + quad*4 + r)*72 + nt*16 + ln15] = (bfr)(val[hl][nt][r]*sum[r]);
      // PV: wave reads ONLY its own P rows -> in-wave lgkmcnt dep, no barrier
      #pragma unroll
      for (int nt = 0; nt < 2; nt++) {
        f32x4 c = ZERO4;
        #pragma unroll
        for (int k0 = 0; k0 < 64; k0 += 32) {
          bf8 ap = *(const bf8*)&P[(wave*16 + ln15)*72 + k0 + quad*8];
          bf8 bv = *(const bf8*)&vT[(hl*32 + nt*16 + ln15)*72 + k0 + quad*8];
          c = MFMA16(ap, bv, c);
        }
        #pragma unroll
        for (int r=0;r<4;r++)
          ov2[(wave*16 + quad*4 + r)*72 + hl*36 + nt*16 + ln15] = (bfr)c[r];
      }
    }
    __syncthreads();

    // ---- proj K-step for this pair (K=64: both heads), weights already in regs ----
    #pragma unroll
    for (int hl = 0; hl < 2; hl++) {
      bf8 afr[4];
      #pragma unroll
      for (int mt=0;mt<4;mt++)
        afr[mt] = *(const bf8*)&ov2[(mt*16+ln15)*72 + hl*36 + quad*8];
      #pragma unroll
      for (int j=0;j<3;j++)
        #pragma unroll
        for (int mt=0;mt<4;mt++) accp[j][mt] = MFMA16(afr[mt], pw[hl][j], accp[j][mt]);
    }
    // no barrier: next pair's QKV writes qs/ks/vT; all reads of them finished pre-ov2-barrier
  }

  // ---- epilogue: bias -> pj overlay -> coalesced residual+scatter ----
  __syncthreads();   // all waves past last proj (ov2 reads) before pj overlays hs..vT
  #pragma unroll
  for (int j=0;j<3;j++) {
    int col = (wave*3+j)*16 + ln15;
    float pb = projb[col];
    #pragma unroll
    for (int mt=0;mt<4;mt++)
      #pragma unroll
      for (int r=0;r<4;r++)
        pj[(mt*16 + quad*4 + r)*196 + col] = accp[j][mt][r] + pb;
  }
  __syncthreads();
  for (int idx = tid; idx < N_*C_; idx += 256) {
    int n = idx / C_, c = idx % C_;
    size_t gr = (size_t)srows[n]*C_ + c;
    out[gr] = x[gr] + pj[n*196 + c];
  }
}

// ================= Kernel 2: LN2 + fc1 + GELU + fc2 + residual, 64 rows/block ================
// LDS: ts[64][200] bf16 (25600) + hidc[64][200] bf16 (25600) = 51200 B.
// st f32[64][196] (50176) overlays ts+hidc after last use.
// Weight fragments burst-loaded into registers per chunk (T14 async-stage).
#define SM2_TS  0
#define SM2_HID 25600
#define SM2_TOT 51200

__global__ __launch_bounds__(256, 2) void k_mlp(
    float* __restrict__ y,
    const float* __restrict__ n2w, const float* __restrict__ n2b,
    const bfr* __restrict__ wsp,
    const float* __restrict__ b1, const float* __restrict__ b2)
{
  __shared__ char smem[SM2_TOT];
  bfr*   ts   = (bfr*)(smem + SM2_TS);
  bfr*   hidc = (bfr*)(smem + SM2_HID);
  float* st   = (float*)smem;       // overlay after ts/hidc dead

  const f32x4 ZERO4 = {0.f, 0.f, 0.f, 0.f};

  int r0 = blockIdx.x * 64;
  int tid = threadIdx.x;
  int lane = tid & 63, wave = tid >> 6;
  int ln15 = lane & 15, quad = lane >> 4;

  // ---- LN2 (unrolled so the 48 row-loads issue early) ----
  #pragma unroll
  for (int i = 0; i < 16; i++) {
    int r = wave + i*4;
    const float* yr = y + (size_t)(r0 + r)*C_;
    float v0 = yr[lane], v1 = yr[lane+64], v2 = yr[lane+128];
    float s = v0+v1+v2, q = v0*v0+v1*v1+v2*v2;
    #pragma unroll
    for (int m = 32; m; m >>= 1) { s += __shfl_xor(s, m); q += __shfl_xor(q, m); }
    float mu = s*(1.f/C_), var = q*(1.f/C_) - mu*mu;
    float rs = rsqrtf(var + 1e-5f);
    ts[r*HSP + lane]     = (bfr)((v0-mu)*rs*n2w[lane]     + n2b[lane]);
    ts[r*HSP + lane+64]  = (bfr)((v1-mu)*rs*n2w[lane+64]  + n2b[lane+64]);
    ts[r*HSP + lane+128] = (bfr)((v2-mu)*rs*n2w[lane+128] + n2b[lane+128]);
  }
  __syncthreads();

  const bfr* w1T = wsp + OW1;
  const bfr* w2T = wsp + OW2;

  f32x4 accp[3][4];   // fc2 accumulators, persist across chunks
  #pragma unroll
  for (int j=0;j<3;j++)
    #pragma unroll
    for (int mt=0;mt<4;mt++) accp[j][mt] = ZERO4;

  for (int c = 0; c < 4; c++) {
    // ---- fc1 weight burst (18x 16B) + b1 prefetch ----
    bf8 wf1[3][6];
    float bb[3];
    #pragma unroll
    for (int j=0;j<3;j++) {
      const bfr* wb = w1T + (size_t)((c*12 + wave*3 + j)*16 + ln15)*192 + quad*8;
      #pragma unroll
      for (int kk=0;kk<6;kk++)
        wf1[j][kk] = *(const bf8*)&wb[kk*32];
      bb[j] = b1[c*192 + (wave*3+j)*16 + ln15];
    }
    // ---- fc1 chunk: M=64, N=192, K=192, weights from regs ----
    f32x4 acc[3][4];
    #pragma unroll
    for (int j=0;j<3;j++)
      #pragma unroll
      for (int mt=0;mt<4;mt++) acc[j][mt] = ZERO4;
    #pragma unroll
    for (int kk = 0; kk < 6; kk++) {
      bf8 afr[4];
      #pragma unroll
      for (int mt=0;mt<4;mt++)
        afr[mt] = *(const bf8*)&ts[(mt*16+ln15)*HSP + kk*32 + quad*8];
      #pragma unroll
      for (int j=0;j<3;j++)
        #pragma unroll
        for (int mt=0;mt<4;mt++) acc[j][mt] = MFMA16(afr[mt], wf1[j][kk], acc[j][mt]);
    }
    // ---- fc2 weight burst issued per-j BEFORE that j's GELU (latency hides under VALU) ----
    bf8 wf2[3][6];
    #pragma unroll
    for (int j=0;j<3;j++) {
      const bfr* wb2 = w2T + (size_t)((wave*3+j)*16 + ln15)*768 + c*192 + quad*8;
      #pragma unroll
      for (int kk=0;kk<6;kk++)
        wf2[j][kk] = *(const bf8*)&wb2[kk*32];
      // GELU (tanh-form sigmoid; |err|<3e-4 << bf16 lsb)
      int colc = (wave*3 + j)*16 + ln15;
      #pragma unroll
      for (int mt=0;mt<4;mt++)
        #pragma unroll
        for (int r=0;r<4;r++) {
          int row = mt*16 + quad*4 + r;
          float g = acc[j][mt][r] + bb[j];
          float u = g*(1.5957691216f + 0.0713548170f*g*g);
          hidc[row*HSP + colc] = (bfr)(g / (1.f + __expf(-u)));
        }
    }
    __syncthreads();
    // ---- fc2 partial: M=64, N=192, K=192, weights from regs ----
    #pragma unroll
    for (int kk = 0; kk < 6; kk++) {
      bf8 afr[4];
      #pragma unroll
      for (int mt=0;mt<4;mt++)
        afr[mt] = *(const bf8*)&hidc[(mt*16+ln15)*HSP + kk*32 + quad*8];
      #pragma unroll
      for (int j=0;j<3;j++)
        #pragma unroll
        for (int mt=0;mt<4;mt++) accp[j][mt] = MFMA16(afr[mt], wf2[j][kk], accp[j][mt]);
    }
    __syncthreads();   // hidc reads done before next chunk's writes (or st overlay)
  }

  // ---- epilogue: bias -> st overlay (over ts/hidc, both dead) ----
  #pragma unroll
  for (int j=0;j<3;j++) {
    int col = (wave*3+j)*16 + ln15;
    float bb2 = b2[col];
    #pragma unroll
    for (int mt=0;mt<4;mt++)
      #pragma unroll
      for (int r=0;r<4;r++) {
        int row = mt*16 + quad*4 + r;
        st[row*196 + col] = accp[j][mt][r] + bb2;
      }
  }
  __syncthreads();
  // residual, coalesced, in-place
  for (int idx = tid; idx < 64*C_; idx += 256) {
    int r = idx / C_, c = idx % C_;
    size_t gr = (size_t)(r0 + r)*C_ + c;
    y[gr] = y[gr] + st[r*196 + c];
  }
}

extern "C" void kernel_launch(void* const* d_in, const int* in_sizes, int n_in,
                              void* d_out, int out_size, void* d_ws, size_t ws_size,
                              hipStream_t stream) {
  const float* x     = (const float*)d_in[0];
  const float* n1w   = (const float*)d_in[1];
  const float* n1b   = (const float*)d_in[2];
  const float* qkvw  = (const float*)d_in[3];
  const float* qkvb  = (const float*)d_in[4];
  const float* btab  = (const float*)d_in[5];
  const float* projw = (const float*)d_in[6];
  const float* projb = (const float*)d_in[7];
  const float* n2w   = (const float*)d_in[8];
  const float* n2b   = (const float*)d_in[9];
  const float* w1    = (const float*)d_in[10];
  const float* b1    = (const float*)d_in[11];
  const float* w2    = (const float*)d_in[12];
  const float* b2    = (const float*)d_in[13];
  const float* mask  = (const float*)d_in[14];
  const int*   rel   = (const int*)d_in[15];
  float* out = (float*)d_out;
  bfr*   wsp = (bfr*)d_ws;   // (442368 + 1572864) * 2 B ~= 4.03 MB

  k_prep<<<(WTOT+255)/256, 256, 0, stream>>>(qkvw, projw, w1, w2, wsp);
  k_prep2<<<(BMTOT+255)/256, 256, 0, stream>>>(btab, rel, mask, wsp + OBM);
  k_attn<<<NWIN, 256, 0, stream>>>(x, n1w, n1b, wsp, qkvb, projb, out);
  k_mlp<<<ROWS/64, 256, 0, stream>>>(out, n2w, n2b, wsp, b1, b2);
}